// Round 9
// baseline (221.606 us; speedup 1.0000x reference)
//
#include <hip/hip_runtime.h>
#include <hip/hip_bf16.h>

// Problem constants: B=2, L=2048, D=1024, H=16, d_k=64
#define Hh 16
#define Ll 2048
#define Dd 1024
#define DK 64
#define Mm 4096  // B*L
#define Kk 1024
#define Nn 1024

typedef short bf16x8 __attribute__((ext_vector_type(8)));
typedef float f32x4 __attribute__((ext_vector_type(4)));

static __device__ __forceinline__ unsigned short f2bf(float f) {
    union { __hip_bfloat16 b; unsigned short u; } cv;
    cv.b = __float2bfloat16(f);
    return cv.u;
}

// truncate-pack two fp32 -> bf16x2 (a in low half). Single v_perm_b32.
static __device__ __forceinline__ unsigned packtr(float a, float b) {
    return __builtin_amdgcn_perm(__builtin_bit_cast(unsigned, b),
                                 __builtin_bit_cast(unsigned, a), 0x07060302u);
}

static __device__ __forceinline__ float fexp2(float x) {
    return __builtin_amdgcn_exp2f(x);  // single v_exp_f32
}

// async global->LDS, 16B/lane. LDS dest = wave-uniform base + lane*16 (HW rule).
static __device__ __forceinline__ void glds16(const ushort* g, ushort* l) {
    __builtin_amdgcn_global_load_lds((const __attribute__((address_space(1))) unsigned int*)g,
                                     (__attribute__((address_space(3))) unsigned int*)l,
                                     16, 0, 0);
}

// ---------------- weight fp32 -> bf16 casts (R15: activations fused into gemm_qkv) ----
__global__ __launch_bounds__(256) void cast_w(
    const float* __restrict__ wq, const float* __restrict__ wk, const float* __restrict__ wv,
    const float* __restrict__ wo,
    ushort* __restrict__ wqb, ushort* __restrict__ wkb, ushort* __restrict__ wvb,
    ushort* __restrict__ wob) {
    const int bx = blockIdx.x;
    const float4* s; ushort4* d; int base;
    if      (bx < 1024) { s = (const float4*)wq; d = (ushort4*)wqb; base = 0; }
    else if (bx < 2048) { s = (const float4*)wk; d = (ushort4*)wkb; base = 1024; }
    else if (bx < 3072) { s = (const float4*)wv; d = (ushort4*)wvb; base = 2048; }
    else                { s = (const float4*)wo; d = (ushort4*)wob; base = 3072; }
    const int i = (bx - base) * 256 + threadIdx.x;
    float4 vv = s[i];
    ushort4 o;
    o.x = f2bf(vv.x); o.y = f2bf(vv.y); o.z = f2bf(vv.z); o.w = f2bf(vv.w);
    d[i] = o;
}

// ---------------- fused QKV projection GEMM (R15: fp32 A reg-staged, BK=64, dbuf) ------
// 1D grid 768; flat = xcd + 8*bcol + 64*slot, group g = slot*8 + xcd.
// z=0: Q (pre-scaled 0.125*log2e) -> [BH,L,64]; z=1: K; z=2: V^T -> [BH,64,L].
// A-panels read DIRECTLY from fp32 activations (cast_all round-trip eliminated,
// -108MB HBM): T14 split -- ISSUE (2x global_load_dwordx4/lane) right after the
// barrier, compute(cur) overlaps the load latency, then f2bf (RNE, bit-identical to
// the old cast_all) + swizzled ds_write_b128 into buf^1. W stays bf16 via glds16
// (pre-swizzled source, linear dest, rule #21). Same 2-phase schedule as R13.
// LDS 64KB (2 bufs x 32KB); 2 blocks/CU.
// Swizzle map (both paths): LDS[row][p] = G[row][p ^ (row&7)] (granule = 8 elems);
// fragment read pos = (kk*4+quad) ^ (l15&7).
__global__ __launch_bounds__(256) void gemm_qkv(
    const float* __restrict__ A0, const float* __restrict__ A1, const float* __restrict__ A2,
    const ushort* __restrict__ W0, const ushort* __restrict__ W1, const ushort* __restrict__ W2,
    const float* __restrict__ b0, const float* __restrict__ b1, const float* __restrict__ b2,
    ushort* __restrict__ O0, ushort* __restrict__ O1, ushort* __restrict__ OVt) {
    __shared__ __align__(16) ushort SM[2 * 16384];  // 64KB: buf0{As,Bs} | buf1{As,Bs}

    const int fl = blockIdx.x;
    const int xcd = fl & 7, bcoli = (fl >> 3) & 7, slot = fl >> 6;
    const int g = slot * 8 + xcd;        // 0..95
    const int z = g >> 5;                // 0..2
    const int browi = g & 31;            // 0..31

    const float* Aact = (z == 0) ? A0 : (z == 1) ? A1 : A2;
    const ushort* W = (z == 0) ? W0 : (z == 1) ? W1 : W2;
    const float* bias = (z == 0) ? b0 : (z == 1) ? b1 : b2;

    const int t = threadIdx.x;
    const int wave = t >> 6, lane = t & 63;
    const int quad = lane >> 4, l15 = lane & 15;
    const int brow = browi * 128, bcol = bcoli * 128;
    const int wr = (wave >> 1) * 64, wc = (wave & 1) * 64;
    // staging geometry: 8 rows x 8 granules per glds16/ds_write; row = lane>>3,
    // granule p = lane&7. W source pre-swizzled: sg = (p^sr)*8 (linear LDS dest).
    // A written directly to swizzled LDS granule (p^sr).
    const int sr = lane >> 3;
    const int ag = (lane & 7) * 8;             // A fp32 source granule (linear)
    const int sg = ((lane & 7) ^ sr) * 8;      // W bf16 source granule (pre-swizzled)
    const int awg = ((lane & 7) ^ sr) * 8;     // A LDS write granule (swizzled dest)

    f32x4 acc[4][4] = {};
    float4 rA[4][2];  // in-flight A fp32 (32 VGPR), static-indexed via full unroll

#define QISSUE(K0, BUF)                                                                    \
    do {                                                                                   \
        ushort* Bs_ = SM + (BUF) * 16384 + 8192;                                           \
        _Pragma("unroll")                                                                  \
        for (int c_ = 0; c_ < 4; c_++) {                                                   \
            const int row_ = wave * 32 + c_ * 8;                                           \
            const float* asrc_ = Aact + (size_t)(brow + row_ + sr) * Kk + (K0) + ag;       \
            rA[c_][0] = *(const float4*)asrc_;                                             \
            rA[c_][1] = *(const float4*)(asrc_ + 4);                                       \
            glds16(W + (size_t)(bcol + row_ + sr) * Kk + (K0) + sg, Bs_ + row_ * 64);      \
        }                                                                                  \
    } while (0)

#define QWRITE(BUF)                                                                        \
    do {                                                                                   \
        ushort* As_ = SM + (BUF) * 16384;                                                  \
        _Pragma("unroll")                                                                  \
        for (int c_ = 0; c_ < 4; c_++) {                                                   \
            const int row_ = wave * 32 + c_ * 8;                                           \
            bf16x8 v_;                                                                     \
            v_[0] = (short)f2bf(rA[c_][0].x);                                              \
            v_[1] = (short)f2bf(rA[c_][0].y);                                              \
            v_[2] = (short)f2bf(rA[c_][0].z);                                              \
            v_[3] = (short)f2bf(rA[c_][0].w);                                              \
            v_[4] = (short)f2bf(rA[c_][1].x);                                              \
            v_[5] = (short)f2bf(rA[c_][1].y);                                              \
            v_[6] = (short)f2bf(rA[c_][1].z);                                              \
            v_[7] = (short)f2bf(rA[c_][1].w);                                              \
            *(bf16x8*)(As_ + (row_ + sr) * 64 + awg) = v_;                                 \
        }                                                                                  \
    } while (0)

    // Prologue: stage tile 0 (stalls once on the A loads; all later tiles overlap).
    QISSUE(0, 0);
    QWRITE(0);
    int cur = 0;

    for (int k0 = 0; k0 < Kk; k0 += 64) {
        __syncthreads();  // buf[cur] ready (W glds16 drained, A ds_writes visible)
        if (k0 + 64 < Kk) QISSUE(k0 + 64, cur ^ 1);  // A loads + W glds16 in flight

        const ushort* As = SM + cur * 16384;
        const ushort* Bs = SM + cur * 16384 + 8192;

        bf16x8 af[2][4], bfr[2][4];
#pragma unroll
        for (int kk = 0; kk < 2; kk++) {
            const int pos8 = (((kk * 4 + quad) ^ (l15 & 7)) * 8);
#pragma unroll
            for (int i = 0; i < 4; i++)
                af[kk][i] = *(const bf16x8*)(As + (wr + i * 16 + l15) * 64 + pos8);
#pragma unroll
            for (int j = 0; j < 4; j++)
                bfr[kk][j] = *(const bf16x8*)(Bs + (wc + j * 16 + l15) * 64 + pos8);
        }
#pragma unroll
        for (int kk = 0; kk < 2; kk++)
#pragma unroll
            for (int i = 0; i < 4; i++)
#pragma unroll
                for (int j = 0; j < 4; j++)
                    acc[i][j] = __builtin_amdgcn_mfma_f32_16x16x32_bf16(af[kk][i], bfr[kk][j], acc[i][j], 0, 0, 0);

        if (k0 + 64 < Kk) QWRITE(cur ^ 1);  // cvt+ds_write after compute: loads landed
        cur ^= 1;
    }
#undef QISSUE
#undef QWRITE

    // C/D layout: row = quad*4+r, col = l15
    if (z < 2) {
        // Repack each wave's 64x64 tile (one head) through LDS -> coalesced 16B stores.
        ushort* Out = (z == 0) ? O0 : O1;
        const float oscl = (z == 0) ? 0.18033688f : 1.0f;  // 0.125*log2(e) folded into Q
        const int b = brow >> 11;
        const int lbase = (brow & 2047) + wr;
        const int h = (bcol + wc) >> 6;           // one head per wave
        ushort* T = SM + wave * 1280;             // [16][80] per wave (odd dword stride)
        __syncthreads();                          // fragment reads done; safe to reuse SM
#pragma unroll
        for (int i = 0; i < 4; i++) {
#pragma unroll
            for (int j = 0; j < 4; j++) {
                const float bv = bias[bcol + wc + j * 16 + l15];
#pragma unroll
                for (int r = 0; r < 4; r++)
                    T[(quad * 4 + r) * 80 + j * 16 + l15] = f2bf((acc[i][j][r] + bv) * oscl);
            }
            const int r8 = lane >> 3, c8 = lane & 7;
#pragma unroll
            for (int pass = 0; pass < 2; pass++) {
                const uint4 val = *(const uint4*)(T + (pass * 8 + r8) * 80 + c8 * 8);
                const int l = lbase + i * 16 + pass * 8 + r8;
                *(uint4*)(Out + ((size_t)(b * Hh + h) * Ll + l) * DK + c8 * 8) = val;
            }
        }
    } else {
        // LDS transpose epilogue: emit V^T [BH, 64, L] with coalesced 16B stores.
        ushort* T = SM;  // T[32][136]
        const int b = brow >> 11;
        const int lbase = brow & 2047;
        const int npr = (wave & 1) * 16 + l15;
#pragma unroll
        for (int j = 0; j < 4; j++) {
            __syncthreads();
            const float bv = bias[bcol + wc + j * 16 + l15];
#pragma unroll
            for (int i = 0; i < 4; i++)
#pragma unroll
                for (int r = 0; r < 4; r++) {
                    const int m = wr + i * 16 + quad * 4 + r;
                    T[npr * 136 + m] = f2bf(acc[i][j][r] + bv);
                }
            __syncthreads();
#pragma unroll
            for (int cc = 0; cc < 2; cc++) {
                const int idx = t + cc * 256;
                const int ni = idx >> 4;
                const int ms = idx & 15;
                const int n = bcol + (ni >> 4) * 64 + j * 16 + (ni & 15);
                const int hh = n >> 6, dk = n & 63;
                uint4 val = *(const uint4*)(T + ni * 136 + ms * 8);
                *(uint4*)(OVt + ((size_t)(b * Hh + hh) * DK + dk) * Ll + lbase + ms * 8) = val;
            }
        }
    }
}

// ---------------- fused attention (R11: within-wave split-K, 2 streams/wave) ----------
// UNCHANGED from R11 (best measured: 47.7us). Grid 512, 256 threads = 4 waves x 32
// q-rows; 2 independent kt-streams per wave (kt<1024 / kt>=1024), dbuf prefetch.
__global__ __launch_bounds__(256, 2) void attn_kernel(const ushort* __restrict__ Q,
                                                      const ushort* __restrict__ Kp,
                                                      const ushort* __restrict__ Vt,
                                                      ushort* __restrict__ Oout,
                                                      const int* __restrict__ masksize) {
    __shared__ __align__(16) ushort SM[32768];  // 64KB
    const int t = threadIdx.x;
    const int wave = t >> 6, lane = t & 63;
    const int quad = lane >> 4, l15 = lane & 15;
    const int bx = blockIdx.x;
    const int bh = bx & 31, qc = bx >> 5;
    const int q0w = qc * 128 + wave * 32;
    const int half = masksize[0] >> 1;
    const unsigned wid = (unsigned)(2 * half);

    const ushort* Qb = Q + (size_t)bh * (Ll * DK);
    const ushort* Kb = Kp + (size_t)bh * (Ll * DK);
    const ushort* Vb = Vt + (size_t)bh * (DK * Ll);

    const bf16x8 qA0 = *(const bf16x8*)(Qb + (size_t)(q0w + l15) * DK + quad * 8);
    const bf16x8 qA1 = *(const bf16x8*)(Qb + (size_t)(q0w + l15) * DK + 32 + quad * 8);
    const bf16x8 qB0 = *(const bf16x8*)(Qb + (size_t)(q0w + 16 + l15) * DK + quad * 8);
    const bf16x8 qB1 = *(const bf16x8*)(Qb + (size_t)(q0w + 16 + l15) * DK + 32 + quad * 8);

    const float C2IN  = (1.0f - 24.0f) * 1.44269504088896f;
    const float C2OUT = -24.0f * 1.44269504088896f;
    const float E1 = 2.718281828f;

    bf16x8 onesf;
#pragma unroll
    for (int j = 0; j < 8; j++) onesf[j] = (short)0x3F80;

    f32x4 OA0[4] = {}, OB0[4] = {}, OA1[4] = {}, OB1[4] = {};
    f32x4 SA0 = {}, SB0 = {}, SA1 = {}, SB1 = {};

    const int krow = lane >> 2;
    const int kcol8 = (((lane & 3) ^ ((lane >> 3) & 3)) * 8);
    const int qsw8 = (quad ^ ((l15 >> 1) & 3)) * 8;
    const int vd8 = lane >> 3;
    const int vgp = 2 * (lane & 7);

#define STAGE_J(J, BUF)                                                                    \
    do {                                                                                   \
        const int kt0_ = (J) * 64, kt1_ = 1024 + (J) * 64;                                 \
        if (wave < 2) {                                                                    \
            const int ktk_ = (wave == 0) ? kt0_ : kt1_;                                    \
            ushort* dst_ = SM + wave * 8192 + (BUF) * 4096;                                \
            _Pragma("unroll")                                                              \
            for (int c_ = 0; c_ < 4; c_++)                                                 \
                _Pragma("unroll")                                                          \
                for (int pan_ = 0; pan_ < 2; pan_++)                                       \
                    glds16(Kb + (size_t)(ktk_ + c_ * 16 + krow) * DK + pan_ * 32 + kcol8,  \
                           dst_ + pan_ * 2048 + c_ * 512);                                 \
        } else {                                                                           \
            const int ktv_ = (wave == 2) ? kt0_ : kt1_;                                    \
            ushort* dst_ = SM + 16384 + (wave - 2) * 8192 + (BUF) * 4096;                  \
            _Pragma("unroll")                                                              \
            for (int s_ = 0; s_ < 8; s_++) {                                               \
                const int d_ = s_ * 8 + vd8;                                               \
                glds16(Vb + (size_t)d_ * Ll + ktv_ + ((vgp ^ (d_ & 14)) * 4),              \
                       dst_ + s_ * 512);                                                   \
            }                                                                              \
        }                                                                                  \
    } while (0)

#define STREAM_BODY(KB, VB, KT, CV, OAx, OBx, SAx, SBx, UNIF)                              \
    _Pragma("unroll")                                                                      \
    for (int s = 0; s < 2; s++) {                                                          \
        const bf16x8 kf00 = *(const bf16x8*)((KB) + ((2 * s) * 16 + l15) * 32 + qsw8);     \
        const bf16x8 kf01 = *(const bf16x8*)((KB) + 2048 + ((2 * s) * 16 + l15) * 32 + qsw8); \
        const bf16x8 kf10 = *(const bf16x8*)((KB) + ((2 * s + 1) * 16 + l15) * 32 + qsw8); \
        const bf16x8 kf11 = *(const bf16x8*)((KB) + 2048 + ((2 * s + 1) * 16 + l15) * 32 + qsw8); \
        f32x4 zA0 = __builtin_amdgcn_mfma_f32_16x16x32_bf16(kf00, qA0, (CV), 0, 0, 0);     \
        zA0 = __builtin_amdgcn_mfma_f32_16x16x32_bf16(kf01, qA1, zA0, 0, 0, 0);            \
        f32x4 zA1 = __builtin_amdgcn_mfma_f32_16x16x32_bf16(kf10, qA0, (CV), 0, 0, 0);     \
        zA1 = __builtin_amdgcn_mfma_f32_16x16x32_bf16(kf11, qA1, zA1, 0, 0, 0);            \
        f32x4 zB0 = __builtin_amdgcn_mfma_f32_16x16x32_bf16(kf00, qB0, (CV), 0, 0, 0);     \
        zB0 = __builtin_amdgcn_mfma_f32_16x16x32_bf16(kf01, qB1, zB0, 0, 0, 0);            \
        f32x4 zB1 = __builtin_amdgcn_mfma_f32_16x16x32_bf16(kf10, qB0, (CV), 0, 0, 0);     \
        zB1 = __builtin_amdgcn_mfma_f32_16x16x32_bf16(kf11, qB1, zB1, 0, 0, 0);            \
        float pA[8], pB[8];                                                                \
        if (UNIF) {                                                                        \
            _Pragma("unroll")                                                              \
            for (int g = 0; g < 2; g++)                                                    \
                _Pragma("unroll")                                                          \
                for (int r = 0; r < 4; r++) {                                              \
                    pA[g * 4 + r] = fexp2(g ? zA1[r] : zA0[r]);                            \
                    pB[g * 4 + r] = fexp2(g ? zB1[r] : zB0[r]);                            \
                }                                                                          \
        } else {                                                                           \
            const int kb = (KT) + s * 32 + quad * 4 + half;                                \
            _Pragma("unroll")                                                              \
            for (int g = 0; g < 2; g++)                                                    \
                _Pragma("unroll")                                                          \
                for (int r = 0; r < 4; r++) {                                              \
                    const unsigned ttA = (unsigned)(kb + g * 16 + r - (q0w + l15));        \
                    const unsigned ttB = (unsigned)(kb + g * 16 + r - (q0w + 16 + l15));   \
                    pA[g * 4 + r] = fexp2(g ? zA1[r] : zA0[r]) * (ttA <= wid ? E1 : 1.0f); \
                    pB[g * 4 + r] = fexp2(g ? zB1[r] : zB0[r]) * (ttB <= wid ? E1 : 1.0f); \
                }                                                                          \
        }                                                                                  \
        bf16x8 pfA, pfB;                                                                   \
        ((unsigned*)&pfA)[0] = packtr(pA[0], pA[1]);                                       \
        ((unsigned*)&pfA)[1] = packtr(pA[2], pA[3]);                                       \
        ((unsigned*)&pfA)[2] = packtr(pA[4], pA[5]);                                       \
        ((unsigned*)&pfA)[3] = packtr(pA[6], pA[7]);                                       \
        ((unsigned*)&pfB)[0] = packtr(pB[0], pB[1]);                                       \
        ((unsigned*)&pfB)[1] = packtr(pB[2], pB[3]);                                       \
        ((unsigned*)&pfB)[2] = packtr(pB[4], pB[5]);                                       \
        ((unsigned*)&pfB)[3] = packtr(pB[6], pB[7]);                                       \
        SAx = __builtin_amdgcn_mfma_f32_16x16x32_bf16(pfA, onesf, SAx, 0, 0, 0);           \
        SBx = __builtin_amdgcn_mfma_f32_16x16x32_bf16(pfB, onesf, SBx, 0, 0, 0);           \
        _Pragma("unroll")                                                                  \
        for (int i = 0; i < 4; i++) {                                                      \
            const int bi = (i * 16 + l15) * 64;                                            \
            const int x14 = l15 & 14;                                                      \
            const ushort4 v1 = *(const ushort4*)((VB) + bi + (((s * 8 + quad) ^ x14) * 4)); \
            const ushort4 v2 = *(const ushort4*)((VB) + bi + (((s * 8 + 4 + quad) ^ x14) * 4)); \
            bf16x8 vc;                                                                     \
            *(ushort4*)&vc = v1;                                                           \
            *((ushort4*)&vc + 1) = v2;                                                     \
            OAx[i] = __builtin_amdgcn_mfma_f32_16x16x32_bf16(pfA, vc, OAx[i], 0, 0, 0);    \
            OBx[i] = __builtin_amdgcn_mfma_f32_16x16x32_bf16(pfB, vc, OBx[i], 0, 0, 0);    \
        }                                                                                  \
    }

    STAGE_J(0, 0);
    int cur = 0;
    const int qlo = q0w, qhi = q0w + 31;

    for (int j = 0; j < 16; ++j) {
        const int kt0 = j * 64, kt1 = 1024 + j * 64;
        __syncthreads();  // buf[cur] staged (loads had prev compute in flight)
        if (j < 15) STAGE_J(j + 1, cur ^ 1);

        const ushort* K0b = SM + cur * 4096;
        const ushort* K1b = SM + 8192 + cur * 4096;
        const ushort* V0b = SM + 16384 + cur * 4096;
        const ushort* V1b = SM + 24576 + cur * 4096;

        const bool allout0 = (kt0 + 63 < qlo - half) || (kt0 > qhi + half);
        const bool allin0  = (kt0 >= qhi - half) && (kt0 + 63 <= qlo + half);
        const bool allout1 = (kt1 + 63 < qlo - half) || (kt1 > qhi + half);
        const bool allin1  = (kt1 >= qhi - half) && (kt1 + 63 <= qlo + half);

        if ((allin0 || allout0) && (allin1 || allout1)) {
            const float c0 = allin0 ? C2IN : C2OUT;
            const float c1 = allin1 ? C2IN : C2OUT;
            const f32x4 cv0 = {c0, c0, c0, c0};
            const f32x4 cv1 = {c1, c1, c1, c1};
            STREAM_BODY(K0b, V0b, kt0, cv0, OA0, OB0, SA0, SB0, 1);
            STREAM_BODY(K1b, V1b, kt1, cv1, OA1, OB1, SA1, SB1, 1);
        } else {
            const f32x4 cvo = {C2OUT, C2OUT, C2OUT, C2OUT};
            STREAM_BODY(K0b, V0b, kt0, cvo, OA0, OB0, SA0, SB0, 0);
            STREAM_BODY(K1b, V1b, kt1, cvo, OA1, OB1, SA1, SB1, 0);
        }
        cur ^= 1;
    }
#undef STAGE_J
#undef STREAM_BODY

    float liA[4], liB[4];
#pragma unroll
    for (int r = 0; r < 4; r++) {
        liA[r] = 1.0f / (SA0[r] + SA1[r]);
        liB[r] = 1.0f / (SB0[r] + SB1[r]);
    }

    const int b = bh >> 4, h = bh & 15;
#pragma unroll
    for (int i = 0; i < 4; i++)
#pragma unroll
        for (int r = 0; r < 4; r++) {
            const int qa = q0w + quad * 4 + r;
            Oout[((size_t)b * Ll + qa) * Dd + h * DK + i * 16 + l15] =
                f2bf((OA0[i][r] + OA1[i][r]) * liA[r]);
            Oout[((size_t)b * Ll + qa + 16) * Dd + h * DK + i * 16 + l15] =
                f2bf((OB0[i][r] + OB1[i][r]) * liB[r]);
        }
}

// ---------------- output projection GEMM (R13: 128x128, BK=64, 2-phase dbuf) ----------
// UNCHANGED. 1D grid 256; flat = xcd + 8*bcoli + 64*slot, browi = slot*8 + xcd.
__global__ __launch_bounds__(256) void gemm_o(const ushort* __restrict__ A,
                                              const ushort* __restrict__ W,
                                              const float* __restrict__ bias,
                                              float* __restrict__ Out) {
    __shared__ __align__(16) ushort SM[2 * 16384];  // 64KB
    const int fl = blockIdx.x;
    const int xcd = fl & 7, bcoli = (fl >> 3) & 7, slot = fl >> 6;
    const int browi = slot * 8 + xcd;  // 0..31
    const int t = threadIdx.x;
    const int wave = t >> 6, lane = t & 63;
    const int quad = lane >> 4, l15 = lane & 15;
    const int brow = browi * 128, bcol = bcoli * 128;
    const int wr = (wave >> 1) * 64, wc = (wave & 1) * 64;
    const int sr = lane >> 3;
    const int sg = ((lane & 7) ^ sr) * 8;

    f32x4 acc[4][4] = {};

#define OSTAGE(K0, BUF)                                                                    \
    do {                                                                                   \
        ushort* As_ = SM + (BUF) * 16384;                                                  \
        ushort* Bs_ = SM + (BUF) * 16384 + 8192;                                           \
        _Pragma("unroll")                                                                  \
        for (int c_ = 0; c_ < 4; c_++) {                                                   \
            const int row_ = wave * 32 + c_ * 8;                                           \
            glds16(A + (size_t)(brow + row_ + sr) * Kk + (K0) + sg, As_ + row_ * 64);      \
            glds16(W + (size_t)(bcol + row_ + sr) * Kk + (K0) + sg, Bs_ + row_ * 64);      \
        }                                                                                  \
    } while (0)

    OSTAGE(0, 0);
    int cur = 0;

    for (int k0 = 0; k0 < Kk; k0 += 64) {
        __syncthreads();
        if (k0 + 64 < Kk) OSTAGE(k0 + 64, cur ^ 1);

        const ushort* As = SM + cur * 16384;
        const ushort* Bs = SM + cur * 16384 + 8192;

        bf16x8 af[2][4], bfr[2][4];
#pragma unroll
        for (int kk = 0; kk < 2; kk++) {
            const int pos8 = (((kk * 4 + quad) ^ (l15 & 7)) * 8);
#pragma unroll
            for (int i = 0; i < 4; i++)
                af[kk][i] = *(const bf16x8*)(As + (wr + i * 16 + l15) * 64 + pos8);
#pragma unroll
            for (int j = 0; j < 4; j++)
                bfr[kk][j] = *(const bf16x8*)(Bs + (wc + j * 16 + l15) * 64 + pos8);
        }
#pragma unroll
        for (int kk = 0; kk < 2; kk++)
#pragma unroll
            for (int i = 0; i < 4; i++)
#pragma unroll
                for (int j = 0; j < 4; j++)
                    acc[i][j] = __builtin_amdgcn_mfma_f32_16x16x32_bf16(af[kk][i], bfr[kk][j], acc[i][j], 0, 0, 0);
        cur ^= 1;
    }
#undef OSTAGE

#pragma unroll
    for (int i = 0; i < 4; i++)
#pragma unroll
        for (int j = 0; j < 4; j++) {
            const int n = bcol + wc + j * 16 + l15;
            const float bv = bias[n];
#pragma unroll
            for (int r = 0; r < 4; r++) {
                const int m = brow + wr + i * 16 + quad * 4 + r;
                Out[(size_t)m * Nn + n] = acc[i][j][r] + bv;
            }
        }
}

// ---------------- launch ----------------
extern "C" void kernel_launch(void* const* d_in, const int* in_sizes, int n_in,
                              void* d_out, int out_size, void* d_ws, size_t ws_size,
                              hipStream_t stream) {
    const float* query = (const float*)d_in[0];
    const float* key   = (const float*)d_in[1];
    const float* value = (const float*)d_in[2];
    const float* Wq = (const float*)d_in[3];
    const float* bq = (const float*)d_in[4];
    const float* Wk = (const float*)d_in[5];
    const float* bk = (const float*)d_in[6];
    const float* Wv = (const float*)d_in[7];
    const float* bv = (const float*)d_in[8];
    const float* Wo = (const float*)d_in[9];
    const float* bo = (const float*)d_in[10];
    const int* masksize = (const int*)d_in[11];

    char* ws = (char*)d_ws;
    const size_t MB = 1024 * 1024;
    ushort* wqb = (ushort*)(ws + 24 * MB);
    ushort* wkb = (ushort*)(ws + 26 * MB);
    ushort* wvb = (ushort*)(ws + 28 * MB);
    ushort* wob = (ushort*)(ws + 30 * MB);
    ushort* Qp  = (ushort*)(ws + 32 * MB);  // [BH, L, 64], pre-scaled by 0.125*log2e
    ushort* Kp  = (ushort*)(ws + 40 * MB);  // [BH, L, 64]
    ushort* Vt  = (ushort*)(ws + 48 * MB);  // [BH, 64, L]
    ushort* AO  = (ushort*)(ws + 56 * MB);  // [4096, 1024]

    cast_w<<<4096, 256, 0, stream>>>(Wq, Wk, Wv, Wo, wqb, wkb, wvb, wob);

    gemm_qkv<<<768, 256, 0, stream>>>(query, key, value,
                                      wqb, wkb, wvb,
                                      bq, bk, bv,
                                      Qp, Kp, Vt);

    attn_kernel<<<512, 256, 0, stream>>>(Qp, Kp, Vt, AO, masksize);

    gemm_o<<<256, 256, 0, stream>>>(AO, wob, bo, (float*)d_out);
}

// Round 10
// 203.652 us; speedup vs baseline: 1.0882x; 1.0882x over previous
//
#include <hip/hip_runtime.h>
#include <hip/hip_bf16.h>

// Problem constants: B=2, L=2048, D=1024, H=16, d_k=64
#define Hh 16
#define Ll 2048
#define Dd 1024
#define DK 64
#define Mm 4096  // B*L
#define Kk 1024
#define Nn 1024

typedef short bf16x8 __attribute__((ext_vector_type(8)));
typedef float f32x4 __attribute__((ext_vector_type(4)));

static __device__ __forceinline__ unsigned short f2bf(float f) {
    union { __hip_bfloat16 b; unsigned short u; } cv;
    cv.b = __float2bfloat16(f);
    return cv.u;
}

// truncate-pack two fp32 -> bf16x2 (a in low half). Single v_perm_b32.
static __device__ __forceinline__ unsigned packtr(float a, float b) {
    return __builtin_amdgcn_perm(__builtin_bit_cast(unsigned, b),
                                 __builtin_bit_cast(unsigned, a), 0x07060302u);
}

static __device__ __forceinline__ float fexp2(float x) {
    return __builtin_amdgcn_exp2f(x);  // single v_exp_f32
}

// async global->LDS, 16B/lane. LDS dest = wave-uniform base + lane*16 (HW rule).
static __device__ __forceinline__ void glds16(const ushort* g, ushort* l) {
    __builtin_amdgcn_global_load_lds((const __attribute__((address_space(1))) unsigned int*)g,
                                     (__attribute__((address_space(3))) unsigned int*)l,
                                     16, 0, 0);
}

// ---------------- fused fp32 -> bf16 casts (R14 restored; R15 fusion reverted:
// reg-staged fp32 A made gemm_qkv 33->71us, worse than the 23us cast saving) --------
__global__ __launch_bounds__(256) void cast_all(
    const float* __restrict__ q, const float* __restrict__ k, const float* __restrict__ v,
    const float* __restrict__ wq, const float* __restrict__ wk, const float* __restrict__ wv,
    const float* __restrict__ wo,
    ushort* __restrict__ qb, ushort* __restrict__ kb, ushort* __restrict__ vb,
    ushort* __restrict__ wqb, ushort* __restrict__ wkb, ushort* __restrict__ wvb,
    ushort* __restrict__ wob) {
    const int bx = blockIdx.x;
    const float4* s; ushort4* d; int base;
    if      (bx <  4096) { s = (const float4*)q;  d = (ushort4*)qb;  base = 0; }
    else if (bx <  8192) { s = (const float4*)k;  d = (ushort4*)kb;  base = 4096; }
    else if (bx < 12288) { s = (const float4*)v;  d = (ushort4*)vb;  base = 8192; }
    else if (bx < 13312) { s = (const float4*)wq; d = (ushort4*)wqb; base = 12288; }
    else if (bx < 14336) { s = (const float4*)wk; d = (ushort4*)wkb; base = 13312; }
    else if (bx < 15360) { s = (const float4*)wv; d = (ushort4*)wvb; base = 14336; }
    else                 { s = (const float4*)wo; d = (ushort4*)wob; base = 15360; }
    const int i = (bx - base) * 256 + threadIdx.x;
    float4 vv = s[i];
    ushort4 o;
    o.x = f2bf(vv.x); o.y = f2bf(vv.y); o.z = f2bf(vv.z); o.w = f2bf(vv.w);
    d[i] = o;
}

// ---------------- fused QKV projection GEMM (R13: BK=64 + 2-phase dbuf prefetch) -------
// 1D grid 768; flat = xcd + 8*bcol + 64*slot, group g = slot*8 + xcd.
// z=0: Q (pre-scaled 0.125*log2e) -> [BH,L,64]; z=1: K; z=2: V^T -> [BH,64,L].
// T3 2-phase: STAGE(k0+64) into buf^1 BEFORE compute(buf). LDS 64KB, 2 blocks/CU.
// T2 granule swizzle: LDS[row][p] = G[row][p^(row&7)] via pre-swizzled global source;
// fragment read pos = (kk*4+quad) ^ (l15&7).
__global__ __launch_bounds__(256) void gemm_qkv(
    const ushort* __restrict__ A0, const ushort* __restrict__ A1, const ushort* __restrict__ A2,
    const ushort* __restrict__ W0, const ushort* __restrict__ W1, const ushort* __restrict__ W2,
    const float* __restrict__ b0, const float* __restrict__ b1, const float* __restrict__ b2,
    ushort* __restrict__ O0, ushort* __restrict__ O1, ushort* __restrict__ OVt) {
    __shared__ __align__(16) ushort SM[2 * 16384];  // 64KB: buf0{As,Bs} | buf1{As,Bs}

    const int fl = blockIdx.x;
    const int xcd = fl & 7, bcoli = (fl >> 3) & 7, slot = fl >> 6;
    const int g = slot * 8 + xcd;        // 0..95
    const int z = g >> 5;                // 0..2
    const int browi = g & 31;            // 0..31

    const ushort* A = (z == 0) ? A0 : (z == 1) ? A1 : A2;
    const ushort* W = (z == 0) ? W0 : (z == 1) ? W1 : W2;
    const float* bias = (z == 0) ? b0 : (z == 1) ? b1 : b2;

    const int t = threadIdx.x;
    const int wave = t >> 6, lane = t & 63;
    const int quad = lane >> 4, l15 = lane & 15;
    const int brow = browi * 128, bcol = bcoli * 128;
    const int wr = (wave >> 1) * 64, wc = (wave & 1) * 64;
    const int sr = lane >> 3;
    const int sg = ((lane & 7) ^ sr) * 8;

    f32x4 acc[4][4] = {};

#define QSTAGE(K0, BUF)                                                                    \
    do {                                                                                   \
        ushort* As_ = SM + (BUF) * 16384;                                                  \
        ushort* Bs_ = SM + (BUF) * 16384 + 8192;                                           \
        _Pragma("unroll")                                                                  \
        for (int c_ = 0; c_ < 4; c_++) {                                                   \
            const int row_ = wave * 32 + c_ * 8;                                           \
            glds16(A + (size_t)(brow + row_ + sr) * Kk + (K0) + sg, As_ + row_ * 64);      \
            glds16(W + (size_t)(bcol + row_ + sr) * Kk + (K0) + sg, Bs_ + row_ * 64);      \
        }                                                                                  \
    } while (0)

    QSTAGE(0, 0);
    int cur = 0;

    for (int k0 = 0; k0 < Kk; k0 += 64) {
        __syncthreads();  // buf[cur] staged (its loads had the previous K-step in flight)
        if (k0 + 64 < Kk) QSTAGE(k0 + 64, cur ^ 1);

        const ushort* As = SM + cur * 16384;
        const ushort* Bs = SM + cur * 16384 + 8192;

        bf16x8 af[2][4], bfr[2][4];
#pragma unroll
        for (int kk = 0; kk < 2; kk++) {
            const int pos8 = (((kk * 4 + quad) ^ (l15 & 7)) * 8);
#pragma unroll
            for (int i = 0; i < 4; i++)
                af[kk][i] = *(const bf16x8*)(As + (wr + i * 16 + l15) * 64 + pos8);
#pragma unroll
            for (int j = 0; j < 4; j++)
                bfr[kk][j] = *(const bf16x8*)(Bs + (wc + j * 16 + l15) * 64 + pos8);
        }
#pragma unroll
        for (int kk = 0; kk < 2; kk++)
#pragma unroll
            for (int i = 0; i < 4; i++)
#pragma unroll
                for (int j = 0; j < 4; j++)
                    acc[i][j] = __builtin_amdgcn_mfma_f32_16x16x32_bf16(af[kk][i], bfr[kk][j], acc[i][j], 0, 0, 0);
        cur ^= 1;
    }
#undef QSTAGE

    // C/D layout: row = quad*4+r, col = l15
    if (z < 2) {
        // Repack each wave's 64x64 tile (one head) through LDS -> coalesced 16B stores.
        ushort* Out = (z == 0) ? O0 : O1;
        const float oscl = (z == 0) ? 0.18033688f : 1.0f;  // 0.125*log2(e) folded into Q
        const int b = brow >> 11;
        const int lbase = (brow & 2047) + wr;
        const int h = (bcol + wc) >> 6;           // one head per wave
        ushort* T = SM + wave * 1280;             // [16][80] per wave (odd dword stride)
        __syncthreads();                          // fragment reads done; safe to reuse SM
#pragma unroll
        for (int i = 0; i < 4; i++) {
#pragma unroll
            for (int j = 0; j < 4; j++) {
                const float bv = bias[bcol + wc + j * 16 + l15];
#pragma unroll
                for (int r = 0; r < 4; r++)
                    T[(quad * 4 + r) * 80 + j * 16 + l15] = f2bf((acc[i][j][r] + bv) * oscl);
            }
            const int r8 = lane >> 3, c8 = lane & 7;
#pragma unroll
            for (int pass = 0; pass < 2; pass++) {
                const uint4 val = *(const uint4*)(T + (pass * 8 + r8) * 80 + c8 * 8);
                const int l = lbase + i * 16 + pass * 8 + r8;
                *(uint4*)(Out + ((size_t)(b * Hh + h) * Ll + l) * DK + c8 * 8) = val;
            }
        }
    } else {
        // LDS transpose epilogue: emit V^T [BH, 64, L] with coalesced 16B stores.
        ushort* T = SM;  // T[32][136]
        const int b = brow >> 11;
        const int lbase = brow & 2047;
        const int npr = (wave & 1) * 16 + l15;
#pragma unroll
        for (int j = 0; j < 4; j++) {
            __syncthreads();
            const float bv = bias[bcol + wc + j * 16 + l15];
#pragma unroll
            for (int i = 0; i < 4; i++)
#pragma unroll
                for (int r = 0; r < 4; r++) {
                    const int m = wr + i * 16 + quad * 4 + r;
                    T[npr * 136 + m] = f2bf(acc[i][j][r] + bv);
                }
            __syncthreads();
#pragma unroll
            for (int cc = 0; cc < 2; cc++) {
                const int idx = t + cc * 256;
                const int ni = idx >> 4;
                const int ms = idx & 15;
                const int n = bcol + (ni >> 4) * 64 + j * 16 + (ni & 15);
                const int hh = n >> 6, dk = n & 63;
                uint4 val = *(const uint4*)(T + ni * 136 + ms * 8);
                *(uint4*)(OVt + ((size_t)(b * Hh + hh) * DK + dk) * Ll + lbase + ms * 8) = val;
            }
        }
    }
}

// ---------------- fused attention (R11: within-wave split-K, 2 streams/wave) ----------
// UNCHANGED from R11 (best measured: 47.7us). Grid 512, 256 threads = 4 waves x 32
// q-rows; 2 independent kt-streams per wave (kt<1024 / kt>=1024), dbuf prefetch.
__global__ __launch_bounds__(256, 2) void attn_kernel(const ushort* __restrict__ Q,
                                                      const ushort* __restrict__ Kp,
                                                      const ushort* __restrict__ Vt,
                                                      ushort* __restrict__ Oout,
                                                      const int* __restrict__ masksize) {
    __shared__ __align__(16) ushort SM[32768];  // 64KB
    const int t = threadIdx.x;
    const int wave = t >> 6, lane = t & 63;
    const int quad = lane >> 4, l15 = lane & 15;
    const int bx = blockIdx.x;
    const int bh = bx & 31, qc = bx >> 5;
    const int q0w = qc * 128 + wave * 32;
    const int half = masksize[0] >> 1;
    const unsigned wid = (unsigned)(2 * half);

    const ushort* Qb = Q + (size_t)bh * (Ll * DK);
    const ushort* Kb = Kp + (size_t)bh * (Ll * DK);
    const ushort* Vb = Vt + (size_t)bh * (DK * Ll);

    const bf16x8 qA0 = *(const bf16x8*)(Qb + (size_t)(q0w + l15) * DK + quad * 8);
    const bf16x8 qA1 = *(const bf16x8*)(Qb + (size_t)(q0w + l15) * DK + 32 + quad * 8);
    const bf16x8 qB0 = *(const bf16x8*)(Qb + (size_t)(q0w + 16 + l15) * DK + quad * 8);
    const bf16x8 qB1 = *(const bf16x8*)(Qb + (size_t)(q0w + 16 + l15) * DK + 32 + quad * 8);

    const float C2IN  = (1.0f - 24.0f) * 1.44269504088896f;
    const float C2OUT = -24.0f * 1.44269504088896f;
    const float E1 = 2.718281828f;

    bf16x8 onesf;
#pragma unroll
    for (int j = 0; j < 8; j++) onesf[j] = (short)0x3F80;

    f32x4 OA0[4] = {}, OB0[4] = {}, OA1[4] = {}, OB1[4] = {};
    f32x4 SA0 = {}, SB0 = {}, SA1 = {}, SB1 = {};

    const int krow = lane >> 2;
    const int kcol8 = (((lane & 3) ^ ((lane >> 3) & 3)) * 8);
    const int qsw8 = (quad ^ ((l15 >> 1) & 3)) * 8;
    const int vd8 = lane >> 3;
    const int vgp = 2 * (lane & 7);

#define STAGE_J(J, BUF)                                                                    \
    do {                                                                                   \
        const int kt0_ = (J) * 64, kt1_ = 1024 + (J) * 64;                                 \
        if (wave < 2) {                                                                    \
            const int ktk_ = (wave == 0) ? kt0_ : kt1_;                                    \
            ushort* dst_ = SM + wave * 8192 + (BUF) * 4096;                                \
            _Pragma("unroll")                                                              \
            for (int c_ = 0; c_ < 4; c_++)                                                 \
                _Pragma("unroll")                                                          \
                for (int pan_ = 0; pan_ < 2; pan_++)                                       \
                    glds16(Kb + (size_t)(ktk_ + c_ * 16 + krow) * DK + pan_ * 32 + kcol8,  \
                           dst_ + pan_ * 2048 + c_ * 512);                                 \
        } else {                                                                           \
            const int ktv_ = (wave == 2) ? kt0_ : kt1_;                                    \
            ushort* dst_ = SM + 16384 + (wave - 2) * 8192 + (BUF) * 4096;                  \
            _Pragma("unroll")                                                              \
            for (int s_ = 0; s_ < 8; s_++) {                                               \
                const int d_ = s_ * 8 + vd8;                                               \
                glds16(Vb + (size_t)d_ * Ll + ktv_ + ((vgp ^ (d_ & 14)) * 4),              \
                       dst_ + s_ * 512);                                                   \
            }                                                                              \
        }                                                                                  \
    } while (0)

#define STREAM_BODY(KB, VB, KT, CV, OAx, OBx, SAx, SBx, UNIF)                              \
    _Pragma("unroll")                                                                      \
    for (int s = 0; s < 2; s++) {                                                          \
        const bf16x8 kf00 = *(const bf16x8*)((KB) + ((2 * s) * 16 + l15) * 32 + qsw8);     \
        const bf16x8 kf01 = *(const bf16x8*)((KB) + 2048 + ((2 * s) * 16 + l15) * 32 + qsw8); \
        const bf16x8 kf10 = *(const bf16x8*)((KB) + ((2 * s + 1) * 16 + l15) * 32 + qsw8); \
        const bf16x8 kf11 = *(const bf16x8*)((KB) + 2048 + ((2 * s + 1) * 16 + l15) * 32 + qsw8); \
        f32x4 zA0 = __builtin_amdgcn_mfma_f32_16x16x32_bf16(kf00, qA0, (CV), 0, 0, 0);     \
        zA0 = __builtin_amdgcn_mfma_f32_16x16x32_bf16(kf01, qA1, zA0, 0, 0, 0);            \
        f32x4 zA1 = __builtin_amdgcn_mfma_f32_16x16x32_bf16(kf10, qA0, (CV), 0, 0, 0);     \
        zA1 = __builtin_amdgcn_mfma_f32_16x16x32_bf16(kf11, qA1, zA1, 0, 0, 0);            \
        f32x4 zB0 = __builtin_amdgcn_mfma_f32_16x16x32_bf16(kf00, qB0, (CV), 0, 0, 0);     \
        zB0 = __builtin_amdgcn_mfma_f32_16x16x32_bf16(kf01, qB1, zB0, 0, 0, 0);            \
        f32x4 zB1 = __builtin_amdgcn_mfma_f32_16x16x32_bf16(kf10, qB0, (CV), 0, 0, 0);     \
        zB1 = __builtin_amdgcn_mfma_f32_16x16x32_bf16(kf11, qB1, zB1, 0, 0, 0);            \
        float pA[8], pB[8];                                                                \
        if (UNIF) {                                                                        \
            _Pragma("unroll")                                                              \
            for (int g = 0; g < 2; g++)                                                    \
                _Pragma("unroll")                                                          \
                for (int r = 0; r < 4; r++) {                                              \
                    pA[g * 4 + r] = fexp2(g ? zA1[r] : zA0[r]);                            \
                    pB[g * 4 + r] = fexp2(g ? zB1[r] : zB0[r]);                            \
                }                                                                          \
        } else {                                                                           \
            const int kb = (KT) + s * 32 + quad * 4 + half;                                \
            _Pragma("unroll")                                                              \
            for (int g = 0; g < 2; g++)                                                    \
                _Pragma("unroll")                                                          \
                for (int r = 0; r < 4; r++) {                                              \
                    const unsigned ttA = (unsigned)(kb + g * 16 + r - (q0w + l15));        \
                    const unsigned ttB = (unsigned)(kb + g * 16 + r - (q0w + 16 + l15));   \
                    pA[g * 4 + r] = fexp2(g ? zA1[r] : zA0[r]) * (ttA <= wid ? E1 : 1.0f); \
                    pB[g * 4 + r] = fexp2(g ? zB1[r] : zB0[r]) * (ttB <= wid ? E1 : 1.0f); \
                }                                                                          \
        }                                                                                  \
        bf16x8 pfA, pfB;                                                                   \
        ((unsigned*)&pfA)[0] = packtr(pA[0], pA[1]);                                       \
        ((unsigned*)&pfA)[1] = packtr(pA[2], pA[3]);                                       \
        ((unsigned*)&pfA)[2] = packtr(pA[4], pA[5]);                                       \
        ((unsigned*)&pfA)[3] = packtr(pA[6], pA[7]);                                       \
        ((unsigned*)&pfB)[0] = packtr(pB[0], pB[1]);                                       \
        ((unsigned*)&pfB)[1] = packtr(pB[2], pB[3]);                                       \
        ((unsigned*)&pfB)[2] = packtr(pB[4], pB[5]);                                       \
        ((unsigned*)&pfB)[3] = packtr(pB[6], pB[7]);                                       \
        SAx = __builtin_amdgcn_mfma_f32_16x16x32_bf16(pfA, onesf, SAx, 0, 0, 0);           \
        SBx = __builtin_amdgcn_mfma_f32_16x16x32_bf16(pfB, onesf, SBx, 0, 0, 0);           \
        _Pragma("unroll")                                                                  \
        for (int i = 0; i < 4; i++) {                                                      \
            const int bi = (i * 16 + l15) * 64;                                            \
            const int x14 = l15 & 14;                                                      \
            const ushort4 v1 = *(const ushort4*)((VB) + bi + (((s * 8 + quad) ^ x14) * 4)); \
            const ushort4 v2 = *(const ushort4*)((VB) + bi + (((s * 8 + 4 + quad) ^ x14) * 4)); \
            bf16x8 vc;                                                                     \
            *(ushort4*)&vc = v1;                                                           \
            *((ushort4*)&vc + 1) = v2;                                                     \
            OAx[i] = __builtin_amdgcn_mfma_f32_16x16x32_bf16(pfA, vc, OAx[i], 0, 0, 0);    \
            OBx[i] = __builtin_amdgcn_mfma_f32_16x16x32_bf16(pfB, vc, OBx[i], 0, 0, 0);    \
        }                                                                                  \
    }

    STAGE_J(0, 0);
    int cur = 0;
    const int qlo = q0w, qhi = q0w + 31;

    for (int j = 0; j < 16; ++j) {
        const int kt0 = j * 64, kt1 = 1024 + j * 64;
        __syncthreads();  // buf[cur] staged (loads had prev compute in flight)
        if (j < 15) STAGE_J(j + 1, cur ^ 1);

        const ushort* K0b = SM + cur * 4096;
        const ushort* K1b = SM + 8192 + cur * 4096;
        const ushort* V0b = SM + 16384 + cur * 4096;
        const ushort* V1b = SM + 24576 + cur * 4096;

        const bool allout0 = (kt0 + 63 < qlo - half) || (kt0 > qhi + half);
        const bool allin0  = (kt0 >= qhi - half) && (kt0 + 63 <= qlo + half);
        const bool allout1 = (kt1 + 63 < qlo - half) || (kt1 > qhi + half);
        const bool allin1  = (kt1 >= qhi - half) && (kt1 + 63 <= qlo + half);

        if ((allin0 || allout0) && (allin1 || allout1)) {
            const float c0 = allin0 ? C2IN : C2OUT;
            const float c1 = allin1 ? C2IN : C2OUT;
            const f32x4 cv0 = {c0, c0, c0, c0};
            const f32x4 cv1 = {c1, c1, c1, c1};
            STREAM_BODY(K0b, V0b, kt0, cv0, OA0, OB0, SA0, SB0, 1);
            STREAM_BODY(K1b, V1b, kt1, cv1, OA1, OB1, SA1, SB1, 1);
        } else {
            const f32x4 cvo = {C2OUT, C2OUT, C2OUT, C2OUT};
            STREAM_BODY(K0b, V0b, kt0, cvo, OA0, OB0, SA0, SB0, 0);
            STREAM_BODY(K1b, V1b, kt1, cvo, OA1, OB1, SA1, SB1, 0);
        }
        cur ^= 1;
    }
#undef STAGE_J
#undef STREAM_BODY

    float liA[4], liB[4];
#pragma unroll
    for (int r = 0; r < 4; r++) {
        liA[r] = 1.0f / (SA0[r] + SA1[r]);
        liB[r] = 1.0f / (SB0[r] + SB1[r]);
    }

    const int b = bh >> 4, h = bh & 15;
#pragma unroll
    for (int i = 0; i < 4; i++)
#pragma unroll
        for (int r = 0; r < 4; r++) {
            const int qa = q0w + quad * 4 + r;
            Oout[((size_t)b * Ll + qa) * Dd + h * DK + i * 16 + l15] =
                f2bf((OA0[i][r] + OA1[i][r]) * liA[r]);
            Oout[((size_t)b * Ll + qa + 16) * Dd + h * DK + i * 16 + l15] =
                f2bf((OB0[i][r] + OB1[i][r]) * liB[r]);
        }
}

// ---------------- output projection GEMM (R16: 128x64, grid 512, 2 blocks/CU) ---------
// R12-R14 ran 128x128 at grid 256 = 1 block x 4 waves/CU = 1 wave/SIMD -- the worst
// latency-hiding config measured (R6 lesson); no co-resident block covers the barrier
// drain. R16: 128x64 tile, grid 512 (2 INDEPENDENT blocks/CU, unsynchronized ->
// drains overlap), BK=64 + 2-phase dbuf + swizzle unchanged. LDS 48KB; acc 4x2.
// __launch_bounds__(256,2): CUDA min-blocks semantics (R8 evidence) -> 128 VGPR cap,
// ~100 needed.
// 1D grid 512; flat = xcd + 8*bcoli + 128*slot; browi = slot*8 + xcd (0..31),
// bcoli 0..15.
__global__ __launch_bounds__(256, 2) void gemm_o(const ushort* __restrict__ A,
                                                 const ushort* __restrict__ W,
                                                 const float* __restrict__ bias,
                                                 float* __restrict__ Out) {
    __shared__ __align__(16) ushort SM[2 * 12288];  // 48KB: buf x {As 16KB, Bs 8KB}
    const int fl = blockIdx.x;
    const int xcd = fl & 7, bcoli = (fl >> 3) & 15, slot = fl >> 7;
    const int browi = slot * 8 + xcd;  // 0..31
    const int t = threadIdx.x;
    const int wave = t >> 6, lane = t & 63;
    const int quad = lane >> 4, l15 = lane & 15;
    const int brow = browi * 128, bcol = bcoli * 64;
    const int wr = (wave >> 1) * 64, wc = (wave & 1) * 32;
    const int sr = lane >> 3;
    const int sg = ((lane & 7) ^ sr) * 8;

    f32x4 acc[4][2] = {};

#define OSTAGE(K0, BUF)                                                                    \
    do {                                                                                   \
        ushort* As_ = SM + (BUF) * 12288;                                                  \
        ushort* Bs_ = SM + (BUF) * 12288 + 8192;                                           \
        _Pragma("unroll")                                                                  \
        for (int c_ = 0; c_ < 4; c_++) {                                                   \
            const int row_ = wave * 32 + c_ * 8;                                           \
            glds16(A + (size_t)(brow + row_ + sr) * Kk + (K0) + sg, As_ + row_ * 64);      \
        }                                                                                  \
        _Pragma("unroll")                                                                  \
        for (int c_ = 0; c_ < 2; c_++) {                                                   \
            const int row_ = wave * 16 + c_ * 8;                                           \
            glds16(W + (size_t)(bcol + row_ + sr) * Kk + (K0) + sg, Bs_ + row_ * 64);      \
        }                                                                                  \
    } while (0)

    OSTAGE(0, 0);
    int cur = 0;

    for (int k0 = 0; k0 < Kk; k0 += 64) {
        __syncthreads();
        if (k0 + 64 < Kk) OSTAGE(k0 + 64, cur ^ 1);

        const ushort* As = SM + cur * 12288;
        const ushort* Bs = SM + cur * 12288 + 8192;

        bf16x8 af[2][4], bfr[2][2];
#pragma unroll
        for (int kk = 0; kk < 2; kk++) {
            const int pos8 = (((kk * 4 + quad) ^ (l15 & 7)) * 8);
#pragma unroll
            for (int i = 0; i < 4; i++)
                af[kk][i] = *(const bf16x8*)(As + (wr + i * 16 + l15) * 64 + pos8);
#pragma unroll
            for (int j = 0; j < 2; j++)
                bfr[kk][j] = *(const bf16x8*)(Bs + (wc + j * 16 + l15) * 64 + pos8);
        }
#pragma unroll
        for (int kk = 0; kk < 2; kk++)
#pragma unroll
            for (int i = 0; i < 4; i++)
#pragma unroll
                for (int j = 0; j < 2; j++)
                    acc[i][j] = __builtin_amdgcn_mfma_f32_16x16x32_bf16(af[kk][i], bfr[kk][j], acc[i][j], 0, 0, 0);
        cur ^= 1;
    }
#undef OSTAGE

#pragma unroll
    for (int i = 0; i < 4; i++)
#pragma unroll
        for (int j = 0; j < 2; j++) {
            const int n = bcol + wc + j * 16 + l15;
            const float bv = bias[n];
#pragma unroll
            for (int r = 0; r < 4; r++) {
                const int m = brow + wr + i * 16 + quad * 4 + r;
                Out[(size_t)m * Nn + n] = acc[i][j][r] + bv;
            }
        }
}

// ---------------- launch ----------------
extern "C" void kernel_launch(void* const* d_in, const int* in_sizes, int n_in,
                              void* d_out, int out_size, void* d_ws, size_t ws_size,
                              hipStream_t stream) {
    const float* query = (const float*)d_in[0];
    const float* key   = (const float*)d_in[1];
    const float* value = (const float*)d_in[2];
    const float* Wq = (const float*)d_in[3];
    const float* bq = (const float*)d_in[4];
    const float* Wk = (const float*)d_in[5];
    const float* bk = (const float*)d_in[6];
    const float* Wv = (const float*)d_in[7];
    const float* bv = (const float*)d_in[8];
    const float* Wo = (const float*)d_in[9];
    const float* bo = (const float*)d_in[10];
    const int* masksize = (const int*)d_in[11];

    char* ws = (char*)d_ws;
    const size_t MB = 1024 * 1024;
    ushort* qb  = (ushort*)(ws + 0 * MB);
    ushort* kbf = (ushort*)(ws + 8 * MB);
    ushort* vbf = (ushort*)(ws + 16 * MB);
    ushort* wqb = (ushort*)(ws + 24 * MB);
    ushort* wkb = (ushort*)(ws + 26 * MB);
    ushort* wvb = (ushort*)(ws + 28 * MB);
    ushort* wob = (ushort*)(ws + 30 * MB);
    ushort* Qp  = (ushort*)(ws + 32 * MB);  // [BH, L, 64], pre-scaled by 0.125*log2e
    ushort* Kp  = (ushort*)(ws + 40 * MB);  // [BH, L, 64]
    ushort* Vt  = (ushort*)(ws + 48 * MB);  // [BH, 64, L]
    ushort* AO  = (ushort*)(ws + 56 * MB);  // [4096, 1024]

    cast_all<<<16384, 256, 0, stream>>>(query, key, value, Wq, Wk, Wv, Wo,
                                        qb, kbf, vbf, wqb, wkb, wvb, wob);

    gemm_qkv<<<768, 256, 0, stream>>>(qb, kbf, vbf,
                                      wqb, wkb, wvb,
                                      bq, bk, bv,
                                      Qp, Kp, Vt);

    attn_kernel<<<512, 256, 0, stream>>>(Qp, Kp, Vt, AO, masksize);

    gemm_o<<<512, 256, 0, stream>>>(AO, wob, bo, (float*)d_out);
}

// Round 13
// 199.501 us; speedup vs baseline: 1.1108x; 1.0208x over previous
//
#include <hip/hip_runtime.h>
#include <hip/hip_bf16.h>

// Problem constants: B=2, L=2048, D=1024, H=16, d_k=64
#define Hh 16
#define Ll 2048
#define Dd 1024
#define DK 64
#define Mm 4096  // B*L
#define Kk 1024
#define Nn 1024

typedef short bf16x8 __attribute__((ext_vector_type(8)));
typedef float f32x4 __attribute__((ext_vector_type(4)));

static __device__ __forceinline__ unsigned short f2bf(float f) {
    union { __hip_bfloat16 b; unsigned short u; } cv;
    cv.b = __float2bfloat16(f);
    return cv.u;
}

// truncate-pack two fp32 -> bf16x2 (a in low half). Single v_perm_b32.
static __device__ __forceinline__ unsigned packtr(float a, float b) {
    return __builtin_amdgcn_perm(__builtin_bit_cast(unsigned, b),
                                 __builtin_bit_cast(unsigned, a), 0x07060302u);
}

static __device__ __forceinline__ float fexp2(float x) {
    return __builtin_amdgcn_exp2f(x);  // single v_exp_f32
}

// async global->LDS, 16B/lane. LDS dest = wave-uniform base + lane*16 (HW rule).
static __device__ __forceinline__ void glds16(const ushort* g, ushort* l) {
    __builtin_amdgcn_global_load_lds((const __attribute__((address_space(1))) unsigned int*)g,
                                     (__attribute__((address_space(3))) unsigned int*)l,
                                     16, 0, 0);
}

// ---------------- fused fp32 -> bf16 casts ----------------
// R17/R18 persistent-kernel fusion failed correctness twice (absmax 0.14/0.24):
// cross-XCD L2 non-coherence under in-kernel grid sync (G16) — bulk regular
// stores/loads across phases are not reliably flushed even with cg::grid().sync().
// Abandoned; separate launches are the correctness boundary that works.
__global__ __launch_bounds__(256) void cast_all(
    const float* __restrict__ q, const float* __restrict__ k, const float* __restrict__ v,
    const float* __restrict__ wq, const float* __restrict__ wk, const float* __restrict__ wv,
    const float* __restrict__ wo,
    ushort* __restrict__ qb, ushort* __restrict__ kb, ushort* __restrict__ vb,
    ushort* __restrict__ wqb, ushort* __restrict__ wkb, ushort* __restrict__ wvb,
    ushort* __restrict__ wob) {
    const int bx = blockIdx.x;
    const float4* s; ushort4* d; int base;
    if      (bx <  4096) { s = (const float4*)q;  d = (ushort4*)qb;  base = 0; }
    else if (bx <  8192) { s = (const float4*)k;  d = (ushort4*)kb;  base = 4096; }
    else if (bx < 12288) { s = (const float4*)v;  d = (ushort4*)vb;  base = 8192; }
    else if (bx < 13312) { s = (const float4*)wq; d = (ushort4*)wqb; base = 12288; }
    else if (bx < 14336) { s = (const float4*)wk; d = (ushort4*)wkb; base = 13312; }
    else if (bx < 15360) { s = (const float4*)wv; d = (ushort4*)wvb; base = 14336; }
    else                 { s = (const float4*)wo; d = (ushort4*)wob; base = 15360; }
    const int i = (bx - base) * 256 + threadIdx.x;
    float4 vv = s[i];
    ushort4 o;
    o.x = f2bf(vv.x); o.y = f2bf(vv.y); o.z = f2bf(vv.z); o.w = f2bf(vv.w);
    d[i] = o;
}

// ---------------- fused QKV projection GEMM (R13: BK=64 + 2-phase dbuf prefetch) -------
// 1D grid 768; flat = xcd + 8*bcol + 64*slot, group g = slot*8 + xcd.
// z=0: Q (pre-scaled 0.125*log2e) -> [BH,L,64]; z=1: K; z=2: V^T -> [BH,64,L].
// T3 2-phase: STAGE(k0+64) into buf^1 BEFORE compute(buf). LDS 64KB, 2 blocks/CU.
// T2 granule swizzle: LDS[row][p] = G[row][p^(row&7)] via pre-swizzled global source;
// fragment read pos = (kk*4+quad) ^ (l15&7).
__global__ __launch_bounds__(256) void gemm_qkv(
    const ushort* __restrict__ A0, const ushort* __restrict__ A1, const ushort* __restrict__ A2,
    const ushort* __restrict__ W0, const ushort* __restrict__ W1, const ushort* __restrict__ W2,
    const float* __restrict__ b0, const float* __restrict__ b1, const float* __restrict__ b2,
    ushort* __restrict__ O0, ushort* __restrict__ O1, ushort* __restrict__ OVt) {
    __shared__ __align__(16) ushort SM[2 * 16384];  // 64KB: buf0{As,Bs} | buf1{As,Bs}

    const int fl = blockIdx.x;
    const int xcd = fl & 7, bcoli = (fl >> 3) & 7, slot = fl >> 6;
    const int g = slot * 8 + xcd;        // 0..95
    const int z = g >> 5;                // 0..2
    const int browi = g & 31;            // 0..31

    const ushort* A = (z == 0) ? A0 : (z == 1) ? A1 : A2;
    const ushort* W = (z == 0) ? W0 : (z == 1) ? W1 : W2;
    const float* bias = (z == 0) ? b0 : (z == 1) ? b1 : b2;

    const int t = threadIdx.x;
    const int wave = t >> 6, lane = t & 63;
    const int quad = lane >> 4, l15 = lane & 15;
    const int brow = browi * 128, bcol = bcoli * 128;
    const int wr = (wave >> 1) * 64, wc = (wave & 1) * 64;
    const int sr = lane >> 3;
    const int sg = ((lane & 7) ^ sr) * 8;

    f32x4 acc[4][4] = {};

#define QSTAGE(K0, BUF)                                                                    \
    do {                                                                                   \
        ushort* As_ = SM + (BUF) * 16384;                                                  \
        ushort* Bs_ = SM + (BUF) * 16384 + 8192;                                           \
        _Pragma("unroll")                                                                  \
        for (int c_ = 0; c_ < 4; c_++) {                                                   \
            const int row_ = wave * 32 + c_ * 8;                                           \
            glds16(A + (size_t)(brow + row_ + sr) * Kk + (K0) + sg, As_ + row_ * 64);      \
            glds16(W + (size_t)(bcol + row_ + sr) * Kk + (K0) + sg, Bs_ + row_ * 64);      \
        }                                                                                  \
    } while (0)

    QSTAGE(0, 0);
    int cur = 0;

    for (int k0 = 0; k0 < Kk; k0 += 64) {
        __syncthreads();  // buf[cur] staged (its loads had the previous K-step in flight)
        if (k0 + 64 < Kk) QSTAGE(k0 + 64, cur ^ 1);

        const ushort* As = SM + cur * 16384;
        const ushort* Bs = SM + cur * 16384 + 8192;

        bf16x8 af[2][4], bfr[2][4];
#pragma unroll
        for (int kk = 0; kk < 2; kk++) {
            const int pos8 = (((kk * 4 + quad) ^ (l15 & 7)) * 8);
#pragma unroll
            for (int i = 0; i < 4; i++)
                af[kk][i] = *(const bf16x8*)(As + (wr + i * 16 + l15) * 64 + pos8);
#pragma unroll
            for (int j = 0; j < 4; j++)
                bfr[kk][j] = *(const bf16x8*)(Bs + (wc + j * 16 + l15) * 64 + pos8);
        }
#pragma unroll
        for (int kk = 0; kk < 2; kk++)
#pragma unroll
            for (int i = 0; i < 4; i++)
#pragma unroll
                for (int j = 0; j < 4; j++)
                    acc[i][j] = __builtin_amdgcn_mfma_f32_16x16x32_bf16(af[kk][i], bfr[kk][j], acc[i][j], 0, 0, 0);
        cur ^= 1;
    }
#undef QSTAGE

    // C/D layout: row = quad*4+r, col = l15
    if (z < 2) {
        // Repack each wave's 64x64 tile (one head) through LDS -> coalesced 16B stores.
        ushort* Out = (z == 0) ? O0 : O1;
        const float oscl = (z == 0) ? 0.18033688f : 1.0f;  // 0.125*log2(e) folded into Q
        const int b = brow >> 11;
        const int lbase = (brow & 2047) + wr;
        const int h = (bcol + wc) >> 6;           // one head per wave
        ushort* T = SM + wave * 1280;             // [16][80] per wave (odd dword stride)
        __syncthreads();                          // fragment reads done; safe to reuse SM
#pragma unroll
        for (int i = 0; i < 4; i++) {
#pragma unroll
            for (int j = 0; j < 4; j++) {
                const float bv = bias[bcol + wc + j * 16 + l15];
#pragma unroll
                for (int r = 0; r < 4; r++)
                    T[(quad * 4 + r) * 80 + j * 16 + l15] = f2bf((acc[i][j][r] + bv) * oscl);
            }
            const int r8 = lane >> 3, c8 = lane & 7;
#pragma unroll
            for (int pass = 0; pass < 2; pass++) {
                const uint4 val = *(const uint4*)(T + (pass * 8 + r8) * 80 + c8 * 8);
                const int l = lbase + i * 16 + pass * 8 + r8;
                *(uint4*)(Out + ((size_t)(b * Hh + h) * Ll + l) * DK + c8 * 8) = val;
            }
        }
    } else {
        // LDS transpose epilogue: emit V^T [BH, 64, L] with coalesced 16B stores.
        ushort* T = SM;  // T[32][136]
        const int b = brow >> 11;
        const int lbase = brow & 2047;
        const int npr = (wave & 1) * 16 + l15;
#pragma unroll
        for (int j = 0; j < 4; j++) {
            __syncthreads();
            const float bv = bias[bcol + wc + j * 16 + l15];
#pragma unroll
            for (int i = 0; i < 4; i++)
#pragma unroll
                for (int r = 0; r < 4; r++) {
                    const int m = wr + i * 16 + quad * 4 + r;
                    T[npr * 136 + m] = f2bf(acc[i][j][r] + bv);
                }
            __syncthreads();
#pragma unroll
            for (int cc = 0; cc < 2; cc++) {
                const int idx = t + cc * 256;
                const int ni = idx >> 4;
                const int ms = idx & 15;
                const int n = bcol + (ni >> 4) * 64 + j * 16 + (ni & 15);
                const int hh = n >> 6, dk = n & 63;
                uint4 val = *(const uint4*)(T + ni * 136 + ms * 8);
                *(uint4*)(OVt + ((size_t)(b * Hh + hh) * DK + dk) * Ll + lbase + ms * 8) = val;
            }
        }
    }
}

// ---------------- fused attention (R19: R11 + T5 s_setprio around MFMA clusters) ------
// Grid 512, 256 threads = 4 waves x 32 q-rows; 2 independent kt-streams per wave
// (kt<1024 / kt>=1024), dbuf prefetch. 2 INDEPENDENT blocks/CU -> wave phase
// diversity -> T5 applies (m191: attn +4-7%; m190: null/negative in lockstep GEMM,
// so GEMMs left untouched). setprio(1) wraps the QK^T cluster and the S+PV cluster.
__global__ __launch_bounds__(256, 2) void attn_kernel(const ushort* __restrict__ Q,
                                                      const ushort* __restrict__ Kp,
                                                      const ushort* __restrict__ Vt,
                                                      ushort* __restrict__ Oout,
                                                      const int* __restrict__ masksize) {
    __shared__ __align__(16) ushort SM[32768];  // 64KB
    const int t = threadIdx.x;
    const int wave = t >> 6, lane = t & 63;
    const int quad = lane >> 4, l15 = lane & 15;
    const int bx = blockIdx.x;
    const int bh = bx & 31, qc = bx >> 5;
    const int q0w = qc * 128 + wave * 32;
    const int half = masksize[0] >> 1;
    const unsigned wid = (unsigned)(2 * half);

    const ushort* Qb = Q + (size_t)bh * (Ll * DK);
    const ushort* Kb = Kp + (size_t)bh * (Ll * DK);
    const ushort* Vb = Vt + (size_t)bh * (DK * Ll);

    const bf16x8 qA0 = *(const bf16x8*)(Qb + (size_t)(q0w + l15) * DK + quad * 8);
    const bf16x8 qA1 = *(const bf16x8*)(Qb + (size_t)(q0w + l15) * DK + 32 + quad * 8);
    const bf16x8 qB0 = *(const bf16x8*)(Qb + (size_t)(q0w + 16 + l15) * DK + quad * 8);
    const bf16x8 qB1 = *(const bf16x8*)(Qb + (size_t)(q0w + 16 + l15) * DK + 32 + quad * 8);

    const float C2IN  = (1.0f - 24.0f) * 1.44269504088896f;
    const float C2OUT = -24.0f * 1.44269504088896f;
    const float E1 = 2.718281828f;

    bf16x8 onesf;
#pragma unroll
    for (int j = 0; j < 8; j++) onesf[j] = (short)0x3F80;

    f32x4 OA0[4] = {}, OB0[4] = {}, OA1[4] = {}, OB1[4] = {};
    f32x4 SA0 = {}, SB0 = {}, SA1 = {}, SB1 = {};

    const int krow = lane >> 2;
    const int kcol8 = (((lane & 3) ^ ((lane >> 3) & 3)) * 8);
    const int qsw8 = (quad ^ ((l15 >> 1) & 3)) * 8;
    const int vd8 = lane >> 3;
    const int vgp = 2 * (lane & 7);

#define STAGE_J(J, BUF)                                                                    \
    do {                                                                                   \
        const int kt0_ = (J) * 64, kt1_ = 1024 + (J) * 64;                                 \
        if (wave < 2) {                                                                    \
            const int ktk_ = (wave == 0) ? kt0_ : kt1_;                                    \
            ushort* dst_ = SM + wave * 8192 + (BUF) * 4096;                                \
            _Pragma("unroll")                                                              \
            for (int c_ = 0; c_ < 4; c_++)                                                 \
                _Pragma("unroll")                                                          \
                for (int pan_ = 0; pan_ < 2; pan_++)                                       \
                    glds16(Kb + (size_t)(ktk_ + c_ * 16 + krow) * DK + pan_ * 32 + kcol8,  \
                           dst_ + pan_ * 2048 + c_ * 512);                                 \
        } else {                                                                           \
            const int ktv_ = (wave == 2) ? kt0_ : kt1_;                                    \
            ushort* dst_ = SM + 16384 + (wave - 2) * 8192 + (BUF) * 4096;                  \
            _Pragma("unroll")                                                              \
            for (int s_ = 0; s_ < 8; s_++) {                                               \
                const int d_ = s_ * 8 + vd8;                                               \
                glds16(Vb + (size_t)d_ * Ll + ktv_ + ((vgp ^ (d_ & 14)) * 4),              \
                       dst_ + s_ * 512);                                                   \
            }                                                                              \
        }                                                                                  \
    } while (0)

#define STREAM_BODY(KB, VB, KT, CV, OAx, OBx, SAx, SBx, UNIF)                              \
    _Pragma("unroll")                                                                      \
    for (int s = 0; s < 2; s++) {                                                          \
        const bf16x8 kf00 = *(const bf16x8*)((KB) + ((2 * s) * 16 + l15) * 32 + qsw8);     \
        const bf16x8 kf01 = *(const bf16x8*)((KB) + 2048 + ((2 * s) * 16 + l15) * 32 + qsw8); \
        const bf16x8 kf10 = *(const bf16x8*)((KB) + ((2 * s + 1) * 16 + l15) * 32 + qsw8); \
        const bf16x8 kf11 = *(const bf16x8*)((KB) + 2048 + ((2 * s + 1) * 16 + l15) * 32 + qsw8); \
        __builtin_amdgcn_s_setprio(1);                                                     \
        f32x4 zA0 = __builtin_amdgcn_mfma_f32_16x16x32_bf16(kf00, qA0, (CV), 0, 0, 0);     \
        zA0 = __builtin_amdgcn_mfma_f32_16x16x32_bf16(kf01, qA1, zA0, 0, 0, 0);            \
        f32x4 zA1 = __builtin_amdgcn_mfma_f32_16x16x32_bf16(kf10, qA0, (CV), 0, 0, 0);     \
        zA1 = __builtin_amdgcn_mfma_f32_16x16x32_bf16(kf11, qA1, zA1, 0, 0, 0);            \
        f32x4 zB0 = __builtin_amdgcn_mfma_f32_16x16x32_bf16(kf00, qB0, (CV), 0, 0, 0);     \
        zB0 = __builtin_amdgcn_mfma_f32_16x16x32_bf16(kf01, qB1, zB0, 0, 0, 0);            \
        f32x4 zB1 = __builtin_amdgcn_mfma_f32_16x16x32_bf16(kf10, qB0, (CV), 0, 0, 0);     \
        zB1 = __builtin_amdgcn_mfma_f32_16x16x32_bf16(kf11, qB1, zB1, 0, 0, 0);            \
        __builtin_amdgcn_s_setprio(0);                                                     \
        float pA[8], pB[8];                                                                \
        if (UNIF) {                                                                        \
            _Pragma("unroll")                                                              \
            for (int g = 0; g < 2; g++)                                                    \
                _Pragma("unroll")                                                          \
                for (int r = 0; r < 4; r++) {                                              \
                    pA[g * 4 + r] = fexp2(g ? zA1[r] : zA0[r]);                            \
                    pB[g * 4 + r] = fexp2(g ? zB1[r] : zB0[r]);                            \
                }                                                                          \
        } else {                                                                           \
            const int kb = (KT) + s * 32 + quad * 4 + half;                                \
            _Pragma("unroll")                                                              \
            for (int g = 0; g < 2; g++)                                                    \
                _Pragma("unroll")                                                          \
                for (int r = 0; r < 4; r++) {                                              \
                    const unsigned ttA = (unsigned)(kb + g * 16 + r - (q0w + l15));        \
                    const unsigned ttB = (unsigned)(kb + g * 16 + r - (q0w + 16 + l15));   \
                    pA[g * 4 + r] = fexp2(g ? zA1[r] : zA0[r]) * (ttA <= wid ? E1 : 1.0f); \
                    pB[g * 4 + r] = fexp2(g ? zB1[r] : zB0[r]) * (ttB <= wid ? E1 : 1.0f); \
                }                                                                          \
        }                                                                                  \
        bf16x8 pfA, pfB;                                                                   \
        ((unsigned*)&pfA)[0] = packtr(pA[0], pA[1]);                                       \
        ((unsigned*)&pfA)[1] = packtr(pA[2], pA[3]);                                       \
        ((unsigned*)&pfA)[2] = packtr(pA[4], pA[5]);                                       \
        ((unsigned*)&pfA)[3] = packtr(pA[6], pA[7]);                                       \
        ((unsigned*)&pfB)[0] = packtr(pB[0], pB[1]);                                       \
        ((unsigned*)&pfB)[1] = packtr(pB[2], pB[3]);                                       \
        ((unsigned*)&pfB)[2] = packtr(pB[4], pB[5]);                                       \
        ((unsigned*)&pfB)[3] = packtr(pB[6], pB[7]);                                       \
        __builtin_amdgcn_s_setprio(1);                                                     \
        SAx = __builtin_amdgcn_mfma_f32_16x16x32_bf16(pfA, onesf, SAx, 0, 0, 0);           \
        SBx = __builtin_amdgcn_mfma_f32_16x16x32_bf16(pfB, onesf, SBx, 0, 0, 0);           \
        _Pragma("unroll")                                                                  \
        for (int i = 0; i < 4; i++) {                                                      \
            const int bi = (i * 16 + l15) * 64;                                            \
            const int x14 = l15 & 14;                                                      \
            const ushort4 v1 = *(const ushort4*)((VB) + bi + (((s * 8 + quad) ^ x14) * 4)); \
            const ushort4 v2 = *(const ushort4*)((VB) + bi + (((s * 8 + 4 + quad) ^ x14) * 4)); \
            bf16x8 vc;                                                                     \
            *(ushort4*)&vc = v1;                                                           \
            *((ushort4*)&vc + 1) = v2;                                                     \
            OAx[i] = __builtin_amdgcn_mfma_f32_16x16x32_bf16(pfA, vc, OAx[i], 0, 0, 0);    \
            OBx[i] = __builtin_amdgcn_mfma_f32_16x16x32_bf16(pfB, vc, OBx[i], 0, 0, 0);    \
        }                                                                                  \
        __builtin_amdgcn_s_setprio(0);                                                     \
    }

    STAGE_J(0, 0);
    int cur = 0;
    const int qlo = q0w, qhi = q0w + 31;

    for (int j = 0; j < 16; ++j) {
        const int kt0 = j * 64, kt1 = 1024 + j * 64;
        __syncthreads();  // buf[cur] staged (loads had prev compute in flight)
        if (j < 15) STAGE_J(j + 1, cur ^ 1);

        const ushort* K0b = SM + cur * 4096;
        const ushort* K1b = SM + 8192 + cur * 4096;
        const ushort* V0b = SM + 16384 + cur * 4096;
        const ushort* V1b = SM + 24576 + cur * 4096;

        const bool allout0 = (kt0 + 63 < qlo - half) || (kt0 > qhi + half);
        const bool allin0  = (kt0 >= qhi - half) && (kt0 + 63 <= qlo + half);
        const bool allout1 = (kt1 + 63 < qlo - half) || (kt1 > qhi + half);
        const bool allin1  = (kt1 >= qhi - half) && (kt1 + 63 <= qlo + half);

        if ((allin0 || allout0) && (allin1 || allout1)) {
            const float c0 = allin0 ? C2IN : C2OUT;
            const float c1 = allin1 ? C2IN : C2OUT;
            const f32x4 cv0 = {c0, c0, c0, c0};
            const f32x4 cv1 = {c1, c1, c1, c1};
            STREAM_BODY(K0b, V0b, kt0, cv0, OA0, OB0, SA0, SB0, 1);
            STREAM_BODY(K1b, V1b, kt1, cv1, OA1, OB1, SA1, SB1, 1);
        } else {
            const f32x4 cvo = {C2OUT, C2OUT, C2OUT, C2OUT};
            STREAM_BODY(K0b, V0b, kt0, cvo, OA0, OB0, SA0, SB0, 0);
            STREAM_BODY(K1b, V1b, kt1, cvo, OA1, OB1, SA1, SB1, 0);
        }
        cur ^= 1;
    }
#undef STAGE_J
#undef STREAM_BODY

    float liA[4], liB[4];
#pragma unroll
    for (int r = 0; r < 4; r++) {
        liA[r] = 1.0f / (SA0[r] + SA1[r]);
        liB[r] = 1.0f / (SB0[r] + SB1[r]);
    }

    const int b = bh >> 4, h = bh & 15;
#pragma unroll
    for (int i = 0; i < 4; i++)
#pragma unroll
        for (int r = 0; r < 4; r++) {
            const int qa = q0w + quad * 4 + r;
            Oout[((size_t)b * Ll + qa) * Dd + h * DK + i * 16 + l15] =
                f2bf((OA0[i][r] + OA1[i][r]) * liA[r]);
            Oout[((size_t)b * Ll + qa + 16) * Dd + h * DK + i * 16 + l15] =
                f2bf((OB0[i][r] + OB1[i][r]) * liB[r]);
        }
}

// ---------------- output projection GEMM (R16: 128x64, grid 512, 2 blocks/CU) ---------
// 1D grid 512; flat = xcd + 8*bcoli + 128*slot; browi = slot*8 + xcd (0..31),
// bcoli 0..15. BK=64 + 2-phase dbuf + swizzle; acc 4x2; LDS 48KB.
__global__ __launch_bounds__(256, 2) void gemm_o(const ushort* __restrict__ A,
                                                 const ushort* __restrict__ W,
                                                 const float* __restrict__ bias,
                                                 float* __restrict__ Out) {
    __shared__ __align__(16) ushort SM[2 * 12288];  // 48KB: buf x {As 16KB, Bs 8KB}
    const int fl = blockIdx.x;
    const int xcd = fl & 7, bcoli = (fl >> 3) & 15, slot = fl >> 7;
    const int browi = slot * 8 + xcd;  // 0..31
    const int t = threadIdx.x;
    const int wave = t >> 6, lane = t & 63;
    const int quad = lane >> 4, l15 = lane & 15;
    const int brow = browi * 128, bcol = bcoli * 64;
    const int wr = (wave >> 1) * 64, wc = (wave & 1) * 32;
    const int sr = lane >> 3;
    const int sg = ((lane & 7) ^ sr) * 8;

    f32x4 acc[4][2] = {};

#define OSTAGE(K0, BUF)                                                                    \
    do {                                                                                   \
        ushort* As_ = SM + (BUF) * 12288;                                                  \
        ushort* Bs_ = SM + (BUF) * 12288 + 8192;                                           \
        _Pragma("unroll")                                                                  \
        for (int c_ = 0; c_ < 4; c_++) {                                                   \
            const int row_ = wave * 32 + c_ * 8;                                           \
            glds16(A + (size_t)(brow + row_ + sr) * Kk + (K0) + sg, As_ + row_ * 64);      \
        }                                                                                  \
        _Pragma("unroll")                                                                  \
        for (int c_ = 0; c_ < 2; c_++) {                                                   \
            const int row_ = wave * 16 + c_ * 8;                                           \
            glds16(W + (size_t)(bcol + row_ + sr) * Kk + (K0) + sg, Bs_ + row_ * 64);      \
        }                                                                                  \
    } while (0)

    OSTAGE(0, 0);
    int cur = 0;

    for (int k0 = 0; k0 < Kk; k0 += 64) {
        __syncthreads();
        if (k0 + 64 < Kk) OSTAGE(k0 + 64, cur ^ 1);

        const ushort* As = SM + cur * 12288;
        const ushort* Bs = SM + cur * 12288 + 8192;

        bf16x8 af[2][4], bfr[2][2];
#pragma unroll
        for (int kk = 0; kk < 2; kk++) {
            const int pos8 = (((kk * 4 + quad) ^ (l15 & 7)) * 8);
#pragma unroll
            for (int i = 0; i < 4; i++)
                af[kk][i] = *(const bf16x8*)(As + (wr + i * 16 + l15) * 64 + pos8);
#pragma unroll
            for (int j = 0; j < 2; j++)
                bfr[kk][j] = *(const bf16x8*)(Bs + (wc + j * 16 + l15) * 64 + pos8);
        }
#pragma unroll
        for (int kk = 0; kk < 2; kk++)
#pragma unroll
            for (int i = 0; i < 4; i++)
#pragma unroll
                for (int j = 0; j < 2; j++)
                    acc[i][j] = __builtin_amdgcn_mfma_f32_16x16x32_bf16(af[kk][i], bfr[kk][j], acc[i][j], 0, 0, 0);
        cur ^= 1;
    }
#undef OSTAGE

#pragma unroll
    for (int i = 0; i < 4; i++)
#pragma unroll
        for (int j = 0; j < 2; j++) {
            const int n = bcol + wc + j * 16 + l15;
            const float bv = bias[n];
#pragma unroll
            for (int r = 0; r < 4; r++) {
                const int m = brow + wr + i * 16 + quad * 4 + r;
                Out[(size_t)m * Nn + n] = acc[i][j][r] + bv;
            }
        }
}

// ---------------- launch ----------------
extern "C" void kernel_launch(void* const* d_in, const int* in_sizes, int n_in,
                              void* d_out, int out_size, void* d_ws, size_t ws_size,
                              hipStream_t stream) {
    const float* query = (const float*)d_in[0];
    const float* key   = (const float*)d_in[1];
    const float* value = (const float*)d_in[2];
    const float* Wq = (const float*)d_in[3];
    const float* bq = (const float*)d_in[4];
    const float* Wk = (const float*)d_in[5];
    const float* bk = (const float*)d_in[6];
    const float* Wv = (const float*)d_in[7];
    const float* bv = (const float*)d_in[8];
    const float* Wo = (const float*)d_in[9];
    const float* bo = (const float*)d_in[10];
    const int* masksize = (const int*)d_in[11];

    char* ws = (char*)d_ws;
    const size_t MB = 1024 * 1024;
    ushort* qb  = (ushort*)(ws + 0 * MB);
    ushort* kbf = (ushort*)(ws + 8 * MB);
    ushort* vbf = (ushort*)(ws + 16 * MB);
    ushort* wqb = (ushort*)(ws + 24 * MB);
    ushort* wkb = (ushort*)(ws + 26 * MB);
    ushort* wvb = (ushort*)(ws + 28 * MB);
    ushort* wob = (ushort*)(ws + 30 * MB);
    ushort* Qp  = (ushort*)(ws + 32 * MB);  // [BH, L, 64], pre-scaled by 0.125*log2e
    ushort* Kp  = (ushort*)(ws + 40 * MB);  // [BH, L, 64]
    ushort* Vt  = (ushort*)(ws + 48 * MB);  // [BH, 64, L]
    ushort* AO  = (ushort*)(ws + 56 * MB);  // [4096, 1024]

    cast_all<<<16384, 256, 0, stream>>>(query, key, value, Wq, Wk, Wv, Wo,
                                        qb, kbf, vbf, wqb, wkb, wvb, wob);

    gemm_qkv<<<768, 256, 0, stream>>>(qb, kbf, vbf,
                                      wqb, wkb, wvb,
                                      bq, bk, bv,
                                      Qp, Kp, Vt);

    attn_kernel<<<512, 256, 0, stream>>>(Qp, Kp, Vt, AO, masksize);

    gemm_o<<<512, 256, 0, stream>>>(AO, wob, bo, (float*)d_out);
}